// Round 9
// baseline (284.921 us; speedup 1.0000x reference)
//
#include <hip/hip_runtime.h>

#define BATCH 2
#define C 20
#define W 512
#define NPIX (512*512)
#define NW 16
#define NH 16
#define K 256
#define NITERS 10
#define SPLIT 4
#define PITCH 260          // LDS row pitch (floats); 1040B rows, 16B aligned
#define NEG_INF_F (-1.0e10f)
#define REC 189            // payload: 9 j * (20 ch + 1 den)
#define RECP 192           // padded split-record stride
#define SPFP 32            // padded spf row: 20 ch + sumsq@20

// ---------------------------------------------------------------- init
// Block = (b, cell, split): 1 px/thread, read-only pass over x. Per-split
// channel sums via wave shuffle reduction -> record slot (j=4 row, den=256).
__global__ __launch_bounds__(256)
void ssn_init_kernel(const float* __restrict__ x,
                     float* __restrict__ part) {
    __shared__ float wsum[4][C];
    __shared__ float chsum[C];
    const int t  = threadIdx.x;
    const int bi = blockIdx.x;
    const int s    = bi & 3;
    const int cell = (bi >> 2) & (K - 1);
    const int b    = bi >> 10;
    const int ky = cell >> 4, kx = cell & 15;
    const int py = t >> 5, px = t & 31;
    const int y  = ky * 32 + s * 8 + py;
    const int xcol = kx * 32 + px;

    float pf[C];
    const float* xb = x + (size_t)b * C * NPIX + (size_t)y * W + xcol;
#pragma unroll
    for (int ch = 0; ch < C; ++ch) pf[ch] = xb[(size_t)ch * NPIX];

    const int wid = t >> 6, lane = t & 63;
#pragma unroll
    for (int ch = 0; ch < C; ++ch) {
        float v = pf[ch];
#pragma unroll
        for (int off = 32; off >= 1; off >>= 1) v += __shfl_down(v, off);
        if (lane == 0) wsum[wid][ch] = v;
    }
    __syncthreads();
    if (t < C) chsum[t] = wsum[0][t] + wsum[1][t] + wsum[2][t] + wsum[3][t];
    __syncthreads();
    if (t < REC) {
        float v = 0.f;
        if (t >= 84 && t < 104)      v = chsum[t - 84];   // j=4 row
        else if (t == 104)           v = 256.0f;          // den
        part[(size_t)((b << 8) + cell) * (SPLIT * RECP) + s * RECP + t] = v;
    }
}

// ---------------------------------------------------------------- reduce
// One block per (b, cell), 64 threads. Gathers 9 j2 x 4 splits, normalizes,
// writes padded spf row + sumsq. final_mode: writes outSpf (b,c,k) instead.
__global__ __launch_bounds__(64)
void ssn_reduce_kernel(const float* __restrict__ part,
                       float* __restrict__ spfP,
                       float* __restrict__ outSpf,
                       int final_mode) {
    __shared__ float num_lds[C];
    __shared__ float den_lds;
    __shared__ float sq_lds[C];
    const int t  = threadIdx.x;
    const int bi = blockIdx.x;             // 0..511
    const int cell = bi & (K - 1);
    const int b    = bi >> 8;
    const int ky = cell >> 4, kx = cell & 15;

    if (t <= C) {   // t<20: num for ch=t; t==20: den
        float acc = 0.f;
#pragma unroll
        for (int j2 = 0; j2 < 9; ++j2) {
            int cy = ky - (j2 / 3 - 1), cx = kx - (j2 % 3 - 1);
            if (cy >= 0 && cy < NH && cx >= 0 && cx < NW) {
                const float* p = part +
                    (size_t)((b << 8) + cy * NW + cx) * (SPLIT * RECP)
                    + j2 * 21 + t;
#pragma unroll
                for (int ss = 0; ss < SPLIT; ++ss) acc += p[ss * RECP];
            }
        }
        if (t < C) num_lds[t] = acc;
        else       den_lds    = acc;
    }
    __syncthreads();
    if (t < C) {
        float v = num_lds[t] / fmaxf(den_lds, 1e-8f);
        if (final_mode) {
            outSpf[((size_t)b * C + t) * K + cell] = v;
        } else {
            spfP[(size_t)bi * SPFP + t] = v;
            sq_lds[t] = v * v;
        }
    }
    __syncthreads();
    if (!final_mode && t == 0) {
        float ss2 = 0.f;
#pragma unroll
        for (int ch = 0; ch < C; ++ch) ss2 += sq_lds[ch];
        spfP[(size_t)bi * SPFP + C] = ss2;
    }
}

// ---------------------------------------------------------------- iterate
// Block = (b, cell, split): 1 px/thread. Phase 0: 189 single loads from the
// padded spf table, ONE barrier. Phase A: scores 2<pf,spf>-|spf|^2, softmax.
// Phase B: 9x21 register-tiled dot products -> own split slot. Block bi also
// copies its x slab to outX when bi%10==it (spread passthrough copy).
__global__ __launch_bounds__(256)
void ssn_iterate_kernel(const float* __restrict__ x,
                        const float* __restrict__ spfP,
                        float* __restrict__ wp,
                        float* __restrict__ outX,
                        float* __restrict__ outQ,
                        int it, int last) {
    __shared__ float spf_lds[9][C];
    __shared__ float sumsq_lds[9];
    __shared__ float pf_tile[C][PITCH];
    __shared__ float w_tile[9][PITCH];

    const int t  = threadIdx.x;
    const int bi = blockIdx.x;
    const int s    = bi & 3;
    const int cell = (bi >> 2) & (K - 1);
    const int b    = bi >> 10;
    const int ky = cell >> 4, kx = cell & 15;
    const int py = t >> 5, px = t & 31;
    const int y  = ky * 32 + s * 8 + py;
    const int xcol = kx * 32 + px;

    // hoisted x loads — in flight across phase 0
    float pf[C];
    const size_t xoff = (size_t)b * C * NPIX + (size_t)y * W + xcol;
    const float* xb = x + xoff;
#pragma unroll
    for (int ch = 0; ch < C; ++ch) pf[ch] = xb[(size_t)ch * NPIX];

    // spread x->outX copy: each block writes its slab in exactly one iterate
    if ((bi % 10) == it) {
        float* ox = outX + xoff;
#pragma unroll
        for (int ch = 0; ch < C; ++ch) ox[(size_t)ch * NPIX] = pf[ch];
    }

    // ---- phase 0: neighbor spf + sumsq (single loads from padded table)
    if (t < 180) {
        int jj = t / 20, ch = t % 20;
        int ny = ky + jj / 3 - 1, nx = kx + jj % 3 - 1;
        float v = 0.f;
        if (ny >= 0 && ny < NH && nx >= 0 && nx < NW)
            v = spfP[(size_t)((b << 8) + ny * NW + nx) * SPFP + ch];
        spf_lds[jj][ch] = v;
    } else if (t < 189) {
        int jj = t - 180;
        int ny = ky + jj / 3 - 1, nx = kx + jj % 3 - 1;
        float v = 0.f;
        if (ny >= 0 && ny < NH && nx >= 0 && nx < NW)
            v = spfP[(size_t)((b << 8) + ny * NW + nx) * SPFP + C];
        sumsq_lds[jj] = v;
    }
    __syncthreads();

    // ---- phase A: scores + softmax
    float sc[9];
#pragma unroll
    for (int j = 0; j < 9; ++j) {
        int ny = ky + j / 3 - 1, nx = kx + j % 3 - 1;
        bool valid = (ny >= 0 && ny < NH && nx >= 0 && nx < NW);
        float dot = 0.f;
#pragma unroll
        for (int ch = 0; ch < C; ++ch) dot = fmaf(pf[ch], spf_lds[j][ch], dot);
        sc[j] = valid ? fmaf(2.f, dot, -sumsq_lds[j]) : NEG_INF_F;
    }
    float m = sc[0];
#pragma unroll
    for (int j = 1; j < 9; ++j) m = fmaxf(m, sc[j]);
    float wv[9], wsum = 0.f;
#pragma unroll
    for (int j = 0; j < 9; ++j) { wv[j] = __expf(sc[j] - m); wsum += wv[j]; }
    float inv = 1.0f / wsum;
#pragma unroll
    for (int j = 0; j < 9; ++j) { wv[j] *= inv; w_tile[j][t] = wv[j]; }
#pragma unroll
    for (int ch = 0; ch < C; ++ch) pf_tile[ch][t] = pf[ch];

    if (last) {
        float* q = outQ + (size_t)b * 9 * NPIX + (size_t)y * W + xcol;
#pragma unroll
        for (int j = 0; j < 9; ++j) q[(size_t)j * NPIX] = wv[j];
    }
    __syncthreads();

    // ---- phase B: 9x21 outputs, 3x3 tiles of (3j x 7r), 16 lanes/tile
    if (t < 144) {
        const int tile = t >> 4, lane = t & 15;
        const int jt = tile / 3, rt = tile % 3;
        float acc[3][7];
#pragma unroll
        for (int jj = 0; jj < 3; ++jj)
#pragma unroll
            for (int rr = 0; rr < 7; ++rr) acc[jj][rr] = 0.f;

#pragma unroll
        for (int cc = 0; cc < 4; ++cc) {
            int c4 = lane + (cc << 4);
            float4 w4[3], f4[7];
#pragma unroll
            for (int jj = 0; jj < 3; ++jj)
                w4[jj] = ((const float4*)&w_tile[3 * jt + jj][0])[c4];
#pragma unroll
            for (int rr = 0; rr < 7; ++rr) {
                int r = 7 * rt + rr;
                if (r < 20) f4[rr] = ((const float4*)&pf_tile[r][0])[c4];
            }
#pragma unroll
            for (int jj = 0; jj < 3; ++jj)
#pragma unroll
                for (int rr = 0; rr < 7; ++rr) {
                    int r = 7 * rt + rr;
                    if (r < 20) {
                        acc[jj][rr] = fmaf(w4[jj].x, f4[rr].x, acc[jj][rr]);
                        acc[jj][rr] = fmaf(w4[jj].y, f4[rr].y, acc[jj][rr]);
                        acc[jj][rr] = fmaf(w4[jj].z, f4[rr].z, acc[jj][rr]);
                        acc[jj][rr] = fmaf(w4[jj].w, f4[rr].w, acc[jj][rr]);
                    } else {          // r == 20: den column (implicit ones)
                        acc[jj][rr] += w4[jj].x + w4[jj].y
                                     + w4[jj].z + w4[jj].w;
                    }
                }
        }
#pragma unroll
        for (int off = 8; off >= 1; off >>= 1)
#pragma unroll
            for (int jj = 0; jj < 3; ++jj)
#pragma unroll
                for (int rr = 0; rr < 7; ++rr)
                    acc[jj][rr] += __shfl_down(acc[jj][rr], off);
        if (lane == 0) {
            float* dst = wp + (size_t)((b << 8) + cell) * (SPLIT * RECP)
                       + s * RECP;
#pragma unroll
            for (int jj = 0; jj < 3; ++jj)
#pragma unroll
                for (int rr = 0; rr < 7; ++rr)
                    dst[(3 * jt + jj) * 21 + 7 * rt + rr] = acc[jj][rr];
        }
    }
}

// ---------------------------------------------------------------- launch
extern "C" void kernel_launch(void* const* d_in, const int* in_sizes, int n_in,
                              void* d_out, int out_size, void* d_ws, size_t ws_size,
                              hipStream_t stream) {
    const float* x = (const float*)d_in[0];
    float* out = (float*)d_out;
    float* outQ   = out;                                   // B*9*NPIX
    float* outSpf = out + (size_t)BATCH * 9 * NPIX;        // B*C*K
    float* outX   = outSpf + (size_t)BATCH * C * K;        // B*C*NPIX

    float* ws   = (float*)d_ws;
    float* part = ws;                                      // B*K*SPLIT*RECP
    float* spfP = part + (size_t)BATCH * K * SPLIT * RECP; // B*K*SPFP

    // init: read x, per-split cell-sum records (no outX write)
    ssn_init_kernel<<<BATCH * K * SPLIT, 256, 0, stream>>>(x, part);
    ssn_reduce_kernel<<<BATCH * K, 64, 0, stream>>>(part, spfP, nullptr, 0);

    for (int it = 0; it < NITERS; ++it) {
        ssn_iterate_kernel<<<BATCH * K * SPLIT, 256, 0, stream>>>(
            x, spfP, part, outX, outQ, it, (it == NITERS - 1) ? 1 : 0);
        if (it < NITERS - 1)
            ssn_reduce_kernel<<<BATCH * K, 64, 0, stream>>>(
                part, spfP, nullptr, 0);
    }
    ssn_reduce_kernel<<<BATCH * K, 64, 0, stream>>>(part, nullptr, outSpf, 1);
}

// Round 10
// 258.900 us; speedup vs baseline: 1.1005x; 1.1005x over previous
//
#include <hip/hip_runtime.h>

#define BATCH 2
#define C 20
#define W 512
#define NPIX (512*512)
#define NW 16
#define NH 16
#define K 256
#define NITERS 10
#define SPLIT 4
#define PITCH 260          // LDS row pitch (floats), breaks pow2 stride
#define NEG_INF_F (-1.0e10f)
#define PART_STRIDE 189    // 9 neighbors * (20 ch + 1 den)

// ---------------------------------------------------------------- init
// Block = (b, cell, split), 1 px/thread. Reads x once; writes outX copy,
// optional xT (b,h,w,c transposed layout), and the uniform-weight partial
// record (j=4 channel sums, den=256) for spf0.
template <int USE_XT>
__global__ __launch_bounds__(256)
void ssn_init_kernel(const float* __restrict__ x,
                     float* __restrict__ outX,
                     float* __restrict__ xT,
                     float* __restrict__ wpart) {
    __shared__ float pf_tile[C][PITCH];
    __shared__ float chpart[80];
    int t = threadIdx.x;
    int bi = blockIdx.x;
    int s    = bi & 3;
    int cell = (bi >> 2) & (K - 1);
    int b    = bi >> 10;
    int ky = cell >> 4, kx = cell & 15;
    int py = t >> 5, px = t & 31;
    int y  = ky * 32 + s * 8 + py;
    int xx = kx * 32 + px;

    const float* xb = x    + (size_t)b * C * NPIX + (size_t)y * W + xx;
    float*       ox = outX + (size_t)b * C * NPIX + (size_t)y * W + xx;
    float pf[C];
#pragma unroll
    for (int ch = 0; ch < C; ++ch) {
        float v = xb[(size_t)ch * NPIX];
        pf[ch] = v;
        ox[(size_t)ch * NPIX] = v;
        pf_tile[ch][t] = v;
    }
    if (USE_XT) {
        float4* xt4 = ((float4*)xT) + ((size_t)b * NPIX + (size_t)y * W + xx) * 5;
#pragma unroll
        for (int q = 0; q < 5; ++q) {
            float4 v4;
            v4.x = pf[q * 4 + 0]; v4.y = pf[q * 4 + 1];
            v4.z = pf[q * 4 + 2]; v4.w = pf[q * 4 + 3];
            xt4[q] = v4;
        }
    }
    __syncthreads();
    if (t < 80) {
        int ch = t >> 2, q = t & 3;
        const float4* p = (const float4*)&pf_tile[ch][0];
        float s4 = 0.f;
#pragma unroll
        for (int i = 0; i < 16; ++i) {
            float4 v = p[q * 16 + i];
            s4 += v.x + v.y + v.z + v.w;
        }
        chpart[t] = s4;
    }
    __syncthreads();
    if (t < PART_STRIDE) {
        float v = 0.f;
        if (t >= 84 && t < 104) {
            int ch = t - 84;
            v = chpart[ch * 4] + chpart[ch * 4 + 1]
              + chpart[ch * 4 + 2] + chpart[ch * 4 + 3];
        } else if (t == 104) {
            v = 256.0f;
        }
        wpart[(size_t)(b * K + cell) * (SPLIT * PART_STRIDE)
              + s * PART_STRIDE + t] = v;
    }
}

// ---------------------------------------------------------------- reduce
// part -> normalized spf (one thread per (b,k,ch)); final mode writes the
// transposed (b,c,k) output layout.  (identical to R3)
__global__ void ssn_reduce_kernel(const float* __restrict__ part,
                                  float* __restrict__ spf,
                                  float* __restrict__ outSpf,
                                  int final_mode) {
    int idx = blockIdx.x * blockDim.x + threadIdx.x;   // B*K*C
    if (idx >= BATCH * K * C) return;
    int ch = idx % C;
    int k  = (idx / C) % K;
    int b  = idx / (C * K);
    int ky = k >> 4, kx = k & 15;
    float num = 0.f, den = 0.f;
#pragma unroll
    for (int j2 = 0; j2 < 9; ++j2) {
        int cy = ky - (j2 / 3 - 1), cx = kx - (j2 % 3 - 1);
        if (cy >= 0 && cy < NH && cx >= 0 && cx < NW) {
            const float* p = part +
                (size_t)(b * K + cy * NW + cx) * (SPLIT * PART_STRIDE) + j2 * 21;
#pragma unroll
            for (int ss = 0; ss < SPLIT; ++ss) {
                num += p[ss * PART_STRIDE + ch];
                den += p[ss * PART_STRIDE + 20];
            }
        }
    }
    float v = num / fmaxf(den, 1e-8f);
    if (final_mode) outSpf[(b * C + ch) * K + k] = v;
    else            spf[(b * K + k) * C + ch]    = v;
}

// ---------------------------------------------------------------- iterate
// Identical to R3's validated kernel except pf loads come from xT (5 float4)
// when USE_XT=1.
template <int USE_XT>
__global__ __launch_bounds__(256)
void ssn_iterate_kernel(const float* __restrict__ x,
                        const float* __restrict__ xT,
                        const float* __restrict__ spf,
                        float* __restrict__ wpart,
                        float* __restrict__ outQ,
                        int last) {
    __shared__ float spf_lds[9][C];
    __shared__ float sumsq_lds[9];
    __shared__ float pf_tile[C + 1][PITCH];
    __shared__ float w_tile[9][PITCH];

    int t = threadIdx.x;
    int bi = blockIdx.x;
    int s    = bi & 3;
    int cell = (bi >> 2) & (K - 1);
    int b    = bi >> 10;
    int ky = cell >> 4, kx = cell & 15;

    int py = t >> 5, px = t & 31;
    int y  = ky * 32 + s * 8 + py;
    int xx = kx * 32 + px;

    // hoisted pixel-feature loads — in flight across phase 0
    float pf[C];
    if (USE_XT) {
        const float4* xt4 = ((const float4*)xT)
                          + ((size_t)b * NPIX + (size_t)y * W + xx) * 5;
        float4 v4[5];
#pragma unroll
        for (int q = 0; q < 5; ++q) v4[q] = xt4[q];
#pragma unroll
        for (int q = 0; q < 5; ++q) {
            pf[q * 4 + 0] = v4[q].x; pf[q * 4 + 1] = v4[q].y;
            pf[q * 4 + 2] = v4[q].z; pf[q * 4 + 3] = v4[q].w;
        }
    } else {
        const float* xb = x + (size_t)b * C * NPIX + (size_t)y * W + xx;
#pragma unroll
        for (int ch = 0; ch < C; ++ch) pf[ch] = xb[(size_t)ch * NPIX];
    }

    if (t < 9 * C) {
        int jj = t / C, ch = t % C;
        int ny = ky + jj / 3 - 1, nx = kx + jj % 3 - 1;
        float v = 0.f;
        if (ny >= 0 && ny < NH && nx >= 0 && nx < NW)
            v = spf[(size_t)(b * K + ny * NW + nx) * C + ch];
        spf_lds[jj][ch] = v;
    }
    if (t < 9) {
        int ny = ky + t / 3 - 1, nx = kx + t % 3 - 1;
        float ss2 = 0.f;
        if (ny >= 0 && ny < NH && nx >= 0 && nx < NW) {
            const float* sp = spf + (size_t)(b * K + ny * NW + nx) * C;
#pragma unroll
            for (int ch = 0; ch < C; ++ch) ss2 += sp[ch] * sp[ch];
        }
        sumsq_lds[t] = ss2;
    }
    __syncthreads();

    float sc[9];
#pragma unroll
    for (int j = 0; j < 9; ++j) {
        int ny = ky + j / 3 - 1, nx = kx + j % 3 - 1;
        bool valid = (ny >= 0 && ny < NH && nx >= 0 && nx < NW);
        float dot = 0.f;
#pragma unroll
        for (int ch = 0; ch < C; ++ch) dot = fmaf(pf[ch], spf_lds[j][ch], dot);
        sc[j] = valid ? fmaf(2.f, dot, -sumsq_lds[j]) : NEG_INF_F;
    }
    float m = sc[0];
#pragma unroll
    for (int j = 1; j < 9; ++j) m = fmaxf(m, sc[j]);
    float wv[9], wsum = 0.f;
#pragma unroll
    for (int j = 0; j < 9; ++j) { wv[j] = __expf(sc[j] - m); wsum += wv[j]; }
    float inv = 1.0f / wsum;
#pragma unroll
    for (int j = 0; j < 9; ++j) { wv[j] *= inv; w_tile[j][t] = wv[j]; }
#pragma unroll
    for (int ch = 0; ch < C; ++ch) pf_tile[ch][t] = pf[ch];
    pf_tile[C][t] = 1.0f;

    if (last) {
        float* q = outQ + (size_t)b * 9 * NPIX + (size_t)y * W + xx;
#pragma unroll
        for (int j = 0; j < 9; ++j) q[(size_t)j * NPIX] = wv[j];
    }
    __syncthreads();

    if (t < 144) {
        int tile = t >> 4;
        int lane = t & 15;
        int jt = tile / 3;
        int rt = tile % 3;
        float acc[3][7];
#pragma unroll
        for (int jj = 0; jj < 3; ++jj)
#pragma unroll
            for (int rr = 0; rr < 7; ++rr) acc[jj][rr] = 0.f;

#pragma unroll
        for (int cc = 0; cc < 4; ++cc) {
            int c4 = lane + (cc << 4);
            float4 w4[3], f4[7];
#pragma unroll
            for (int jj = 0; jj < 3; ++jj)
                w4[jj] = ((const float4*)&w_tile[3 * jt + jj][0])[c4];
#pragma unroll
            for (int rr = 0; rr < 7; ++rr)
                f4[rr] = ((const float4*)&pf_tile[7 * rt + rr][0])[c4];
#pragma unroll
            for (int jj = 0; jj < 3; ++jj)
#pragma unroll
                for (int rr = 0; rr < 7; ++rr) {
                    acc[jj][rr] = fmaf(w4[jj].x, f4[rr].x, acc[jj][rr]);
                    acc[jj][rr] = fmaf(w4[jj].y, f4[rr].y, acc[jj][rr]);
                    acc[jj][rr] = fmaf(w4[jj].z, f4[rr].z, acc[jj][rr]);
                    acc[jj][rr] = fmaf(w4[jj].w, f4[rr].w, acc[jj][rr]);
                }
        }
#pragma unroll
        for (int off = 8; off >= 1; off >>= 1)
#pragma unroll
            for (int jj = 0; jj < 3; ++jj)
#pragma unroll
                for (int rr = 0; rr < 7; ++rr)
                    acc[jj][rr] += __shfl_down(acc[jj][rr], off);
        if (lane == 0) {
            float* dst = wpart + (size_t)(b * K + cell) * (SPLIT * PART_STRIDE)
                       + s * PART_STRIDE;
#pragma unroll
            for (int jj = 0; jj < 3; ++jj)
#pragma unroll
                for (int rr = 0; rr < 7; ++rr)
                    dst[(3 * jt + jj) * 21 + 7 * rt + rr] = acc[jj][rr];
        }
    }
}

// ---------------------------------------------------------------- launch
extern "C" void kernel_launch(void* const* d_in, const int* in_sizes, int n_in,
                              void* d_out, int out_size, void* d_ws, size_t ws_size,
                              hipStream_t stream) {
    const float* x = (const float*)d_in[0];
    float* out = (float*)d_out;
    float* outQ   = out;                                   // B*9*NPIX
    float* outSpf = out + (size_t)BATCH * 9 * NPIX;        // B*C*K
    float* outX   = outSpf + (size_t)BATCH * C * K;        // B*C*NPIX

    float* ws   = (float*)d_ws;
    float* spf  = ws;                                      // B*K*C
    float* part = spf + (size_t)BATCH * K * C;             // B*K*SPLIT*189
    float* xT   = part + (size_t)BATCH * K * SPLIT * PART_STRIDE;

    const size_t need_f = (size_t)BATCH * K * C
                        + (size_t)BATCH * K * SPLIT * PART_STRIDE
                        + (size_t)BATCH * NPIX * C;
    const int use_xt = (ws_size >= need_f * sizeof(float)) ? 1 : 0;

    if (use_xt) {
        ssn_init_kernel<1><<<BATCH * K * SPLIT, 256, 0, stream>>>(
            x, outX, xT, part);
        ssn_reduce_kernel<<<160, 64, 0, stream>>>(part, spf, nullptr, 0);
        for (int it = 0; it < NITERS; ++it) {
            ssn_iterate_kernel<1><<<BATCH * K * SPLIT, 256, 0, stream>>>(
                x, xT, spf, part, outQ, (it == NITERS - 1) ? 1 : 0);
            if (it < NITERS - 1)
                ssn_reduce_kernel<<<160, 64, 0, stream>>>(part, spf, nullptr, 0);
        }
    } else {
        ssn_init_kernel<0><<<BATCH * K * SPLIT, 256, 0, stream>>>(
            x, outX, xT, part);
        ssn_reduce_kernel<<<160, 64, 0, stream>>>(part, spf, nullptr, 0);
        for (int it = 0; it < NITERS; ++it) {
            ssn_iterate_kernel<0><<<BATCH * K * SPLIT, 256, 0, stream>>>(
                x, xT, spf, part, outQ, (it == NITERS - 1) ? 1 : 0);
            if (it < NITERS - 1)
                ssn_reduce_kernel<<<160, 64, 0, stream>>>(part, spf, nullptr, 0);
        }
    }
    ssn_reduce_kernel<<<160, 64, 0, stream>>>(part, nullptr, outSpf, 1);
}